// Round 1
// baseline (1167.329 us; speedup 1.0000x reference)
//
#include <hip/hip_runtime.h>
#include <math.h>

#define B  128
#define L  64
#define NS 32
#define NI 16
#define D  256

__device__ __forceinline__ float wave_reduce_sum(float v) {
#pragma unroll
  for (int off = 32; off; off >>= 1) v += __shfl_xor(v, off, 64);
  return v;
}
__device__ __forceinline__ float wave_reduce_max(float v) {
#pragma unroll
  for (int off = 32; off; off >>= 1) v = fmaxf(v, __shfl_xor(v, off, 64));
  return v;
}

// ---------------------------------------------------------------------------
// K1: per (b,l): a_words = mean(x); logits[n] = <w_route_ws[l,n,:], x>;
//     softmax over n; wls[b,l,n] = c_ws * a_words.  grid = B*L, 256 thr.
// ---------------------------------------------------------------------------
__global__ __launch_bounds__(256) void k1_route_words(
    const float* __restrict__ tf, const float* __restrict__ wr,
    float* __restrict__ wls, float* __restrict__ a_words) {
  int bl = blockIdx.x;           // b*L + l
  int l  = bl & (L - 1);
  int t  = threadIdx.x;
  int wave = t >> 6, lane = t & 63;
  __shared__ float sx[D];
  __shared__ float slog[NS];
  __shared__ float s_aw;
  sx[t] = tf[bl * D + t];
  __syncthreads();
  const float* wbase = wr + l * NS * D;
#pragma unroll
  for (int r = 0; r < 8; ++r) {
    int n = wave * 8 + r;
    const float* w = wbase + n * D;
    float p = 0.f;
#pragma unroll
    for (int jj = 0; jj < 4; ++jj) {
      int j = lane + jj * 64;
      p = fmaf(w[j], sx[j], p);
    }
    p = wave_reduce_sum(p);
    if (lane == 0) slog[n] = p;
  }
  if (wave == 0) {
    float p = sx[lane] + sx[lane + 64] + sx[lane + 128] + sx[lane + 192];
    p = wave_reduce_sum(p);
    if (lane == 0) s_aw = p * (1.f / D);
  }
  __syncthreads();
  if (wave == 0) {
    float aw = s_aw;
    float v = (lane < NS) ? slog[lane] : -INFINITY;
    float m = wave_reduce_max(v);
    float e = (lane < NS) ? __expf(v - m) : 0.f;
    float s = wave_reduce_sum(e);
    if (lane < NS) wls[bl * NS + lane] = (e / s) * aw;
    if (lane == 0) a_words[bl] = aw;
  }
}

// ---------------------------------------------------------------------------
// K2: per b: sum_a = sum_l a_words; weighted_c[b,s] = sum_l wls;
//     a_slots = weighted_c / sum_a.  grid = B, 64 thr.
// ---------------------------------------------------------------------------
__global__ __launch_bounds__(64) void k2_slots_agg(
    const float* __restrict__ wls, const float* __restrict__ a_words,
    float* __restrict__ weighted_c, float* __restrict__ a_slots) {
  int b = blockIdx.x;
  int lane = threadIdx.x;
  float aw = a_words[b * L + lane];
  float sa = wave_reduce_sum(aw);
  if (lane < NS) {
    float wc = 0.f;
    for (int l = 0; l < L; ++l) wc += wls[(b * L + l) * NS + lane];
    weighted_c[b * NS + lane] = wc;
    a_slots[b * NS + lane] = wc / sa;
  }
}

// ---------------------------------------------------------------------------
// K3: the big fused GEMM.  Per s:
//   u_slots[b,s,i] = (sum_{l,j} Wp[l,s,i,j] * wls[b,l,s]*x[b,l,j]) / wc[b,s]
// Tile: BM=64 (b) x BN=64 (i), KC=64, 256 thr, 4x4 micro-tile.
// grid = 32 s * 2 b-tiles * 4 i-tiles = 256 blocks (b-tile innermost so the
// W-sharing pair is adjacent -> L3 catches the 2x W re-read).
// ---------------------------------------------------------------------------
#define BM 64
#define BN 64
#define KC 64
#define PITCH (BM + 4)  // 68 floats: float4-aligned rows, conflict-light

__global__ __launch_bounds__(256) void k3_uslots(
    const float* __restrict__ tf, const float* __restrict__ wp,
    const float* __restrict__ wls, const float* __restrict__ wc,
    float* __restrict__ u_slots) {
  __shared__ float Yt[KC][PITCH];
  __shared__ float Wt[KC][PITCH];
  __shared__ float sw[BM];
  int bx = blockIdx.x;
  int s  = bx >> 3;
  int it = (bx >> 1) & 3;
  int bt = bx & 1;
  int i0 = it * BN;
  int b0 = bt * BM;
  int t  = threadIdx.x;
  int tx = t & 15, ty = t >> 4;   // compute mapping
  int kk = t & 63, grp = t >> 6;  // staging mapping

  float acc[4][4] = {};

  for (int l = 0; l < L; ++l) {
    if (t < BM) sw[t] = wls[((b0 + t) * L + l) * NS + s];
    const float* wbase = wp + (size_t)(l * NS + s) * D * D;
    for (int jc = 0; jc < D; jc += KC) {
      __syncthreads();
      // stage Y[k][b] = wls[b,l,s] * x[b,l,jc+k]   (lanes over k: coalesced)
#pragma unroll
      for (int g = 0; g < 16; ++g) {
        int bb = grp * 16 + g;
        Yt[kk][bb] = sw[bb] * tf[(size_t)(b0 + bb) * (L * D) + l * D + jc + kk];
      }
      // stage W[k][i] = Wp[l,s,i0+i,jc+k]          (lanes over k: coalesced)
#pragma unroll
      for (int g = 0; g < 16; ++g) {
        int ii = grp * 16 + g;
        Wt[kk][ii] = wbase[(size_t)(i0 + ii) * D + jc + kk];
      }
      __syncthreads();
#pragma unroll 8
      for (int k = 0; k < KC; ++k) {
        const float4 av = *(const float4*)(&Yt[k][ty * 4]);
        const float4 bv = *(const float4*)(&Wt[k][tx * 4]);
        float a[4] = {av.x, av.y, av.z, av.w};
        float bf[4] = {bv.x, bv.y, bv.z, bv.w};
#pragma unroll
        for (int m = 0; m < 4; ++m)
#pragma unroll
          for (int n = 0; n < 4; ++n)
            acc[m][n] = fmaf(a[m], bf[n], acc[m][n]);
      }
    }
  }
  // epilogue: divide by weighted_c[b,s], write float4
#pragma unroll
  for (int m = 0; m < 4; ++m) {
    int b = b0 + ty * 4 + m;
    float inv = 1.f / wc[b * NS + s];
    float4 o;
    o.x = acc[m][0] * inv;
    o.y = acc[m][1] * inv;
    o.z = acc[m][2] * inv;
    o.w = acc[m][3] * inv;
    *(float4*)(&u_slots[(size_t)(b * NS + s) * D + i0 + tx * 4]) = o;
  }
}

// ---------------------------------------------------------------------------
// K4: per (b,s): logits2[i] = <w_route_si[s,i,:], u_slots[b,s,:]>; softmax
//     over i (NI); w2[b,s,i] = c_si * a_slots[b,s].  grid = B*NS, 64 thr.
// ---------------------------------------------------------------------------
__global__ __launch_bounds__(64) void k4_route_si(
    const float* __restrict__ u_slots, const float* __restrict__ wr_si,
    const float* __restrict__ a_slots, float* __restrict__ w2) {
  int bs = blockIdx.x;     // b*NS + s
  int s  = bs & (NS - 1);
  int lane = threadIdx.x;
  __shared__ float su[D];
  __shared__ float slog[NI];
#pragma unroll
  for (int jj = 0; jj < 4; ++jj) su[lane + jj * 64] = u_slots[bs * D + lane + jj * 64];
  __syncthreads();
  for (int i = 0; i < NI; ++i) {
    const float* w = wr_si + (s * NI + i) * D;
    float p = 0.f;
#pragma unroll
    for (int jj = 0; jj < 4; ++jj) {
      int j = lane + jj * 64;
      p = fmaf(w[j], su[j], p);
    }
    p = wave_reduce_sum(p);
    if (lane == 0) slog[i] = p;
  }
  __syncthreads();
  float v = (lane < NI) ? slog[lane] : -INFINITY;
  float m = wave_reduce_max(v);
  float e = (lane < NI) ? __expf(v - m) : 0.f;
  float ssum = wave_reduce_sum(e);
  if (lane < NI) w2[bs * NI + lane] = (e / ssum) * a_slots[bs];
}

// ---------------------------------------------------------------------------
// K5: per b: sum_as = sum_s a_slots; wc2[b,i] = sum_s w2;
//     a_intents = wc2 / sum_as.  grid = B, 64 thr.
// ---------------------------------------------------------------------------
__global__ __launch_bounds__(64) void k5_intents_agg(
    const float* __restrict__ w2, const float* __restrict__ a_slots,
    float* __restrict__ wc2, float* __restrict__ a_intents) {
  int b = blockIdx.x;
  int lane = threadIdx.x;
  float as = (lane < NS) ? a_slots[b * NS + lane] : 0.f;
  float sas = wave_reduce_sum(as);
  if (lane < NI) {
    float wc = 0.f;
    for (int s = 0; s < NS; ++s) wc += w2[(b * NS + s) * NI + lane];
    wc2[b * NI + lane] = wc;
    a_intents[b * NI + lane] = wc / sas;
  }
}

// ---------------------------------------------------------------------------
// K6: Wsum[s,i,k] = sum_j w_pose_si[s,i,j,k]   (the reference einsum
//     'sijk,bsk->bsik' contracts ONLY j).  grid = NS*NI, 256 thr.
// ---------------------------------------------------------------------------
__global__ __launch_bounds__(256) void k6_wsum(
    const float* __restrict__ wps, float* __restrict__ wsum) {
  int si = blockIdx.x;           // s*NI + i
  int k  = threadIdx.x;
  const float* base = wps + (size_t)si * D * D + k;
  float a0 = 0.f, a1 = 0.f, a2 = 0.f, a3 = 0.f;
  for (int j = 0; j < D; j += 4) {
    a0 += base[(size_t)j * D];
    a1 += base[(size_t)(j + 1) * D];
    a2 += base[(size_t)(j + 2) * D];
    a3 += base[(size_t)(j + 3) * D];
  }
  wsum[si * D + k] = (a0 + a1) + (a2 + a3);
}

// ---------------------------------------------------------------------------
// K7: u_intents[b,i,k] = sum_s w2[b,s,i]*u_slots[b,s,k]*Wsum[s,i,k] / wc2[b,i]
//     grid = B*NI, 256 thr.
// ---------------------------------------------------------------------------
__global__ __launch_bounds__(256) void k7_uintents(
    const float* __restrict__ u_slots, const float* __restrict__ w2,
    const float* __restrict__ wsum, const float* __restrict__ wc2,
    float* __restrict__ u_intents) {
  int bi = blockIdx.x;           // b*NI + i
  int b = bi >> 4, i = bi & (NI - 1);
  int k = threadIdx.x;
  float acc = 0.f;
  for (int s = 0; s < NS; ++s) {
    float w = w2[(b * NS + s) * NI + i];
    acc = fmaf(w * u_slots[(b * NS + s) * D + k], wsum[(s * NI + i) * D + k], acc);
  }
  u_intents[bi * D + k] = acc / wc2[bi];
}

// ---------------------------------------------------------------------------
extern "C" void kernel_launch(void* const* d_in, const int* in_sizes, int n_in,
                              void* d_out, int out_size, void* d_ws, size_t ws_size,
                              hipStream_t stream) {
  const float* tf    = (const float*)d_in[0];  // (B,L,D)
  const float* wr_ws = (const float*)d_in[1];  // (L,NS,D)
  const float* wp_ws = (const float*)d_in[2];  // (L,NS,D,D)
  const float* wr_si = (const float*)d_in[3];  // (NS,NI,D)
  const float* wp_si = (const float*)d_in[4];  // (NS,NI,D,D)

  float* out       = (float*)d_out;
  float* a_slots   = out;                            // B*NS    = 4096
  float* u_slots   = a_slots + B * NS;               // B*NS*D  = 1048576
  float* a_intents = u_slots + B * NS * D;           // B*NI    = 2048
  float* u_intents = a_intents + B * NI;             // B*NI*D  = 524288

  float* ws         = (float*)d_ws;
  float* wls        = ws;                  // B*L*NS  = 262144
  float* a_words    = wls + B * L * NS;    // B*L     = 8192
  float* weighted_c = a_words + B * L;     // B*NS    = 4096
  float* w2         = weighted_c + B * NS; // B*NS*NI = 65536
  float* wc2        = w2 + B * NS * NI;    // B*NI    = 2048
  float* wsum       = wc2 + B * NI;        // NS*NI*D = 131072

  k1_route_words<<<B * L, 256, 0, stream>>>(tf, wr_ws, wls, a_words);
  k2_slots_agg<<<B, 64, 0, stream>>>(wls, a_words, weighted_c, a_slots);
  k3_uslots<<<256, 256, 0, stream>>>(tf, wp_ws, wls, weighted_c, u_slots);
  k6_wsum<<<NS * NI, 256, 0, stream>>>(wp_si, wsum);
  k4_route_si<<<B * NS, 64, 0, stream>>>(u_slots, wr_si, a_slots, w2);
  k5_intents_agg<<<B, 64, 0, stream>>>(w2, a_slots, wc2, a_intents);
  k7_uintents<<<B * NI, 256, 0, stream>>>(u_slots, w2, wsum, wc2, u_intents);
}

// Round 2
// 270.378 us; speedup vs baseline: 4.3174x; 4.3174x over previous
//
#include <hip/hip_runtime.h>
#include <math.h>

#define B  128
#define L  64
#define NS 32
#define NI 16
#define D  256

typedef __attribute__((ext_vector_type(8))) short bf16x8;
typedef __attribute__((ext_vector_type(4))) float f32x4;

__device__ __forceinline__ float wave_reduce_sum(float v) {
#pragma unroll
  for (int off = 32; off; off >>= 1) v += __shfl_xor(v, off, 64);
  return v;
}
__device__ __forceinline__ float wave_reduce_max(float v) {
#pragma unroll
  for (int off = 32; off; off >>= 1) v = fmaxf(v, __shfl_xor(v, off, 64));
  return v;
}

// RTNE f32 -> bf16 bits
__device__ __forceinline__ ushort bf16_rtne(float f) {
  unsigned u = __float_as_uint(f);
  unsigned r = 0x7FFFu + ((u >> 16) & 1u);
  return (ushort)((u + r) >> 16);
}
// split x into hi + lo (both bf16, RTNE): x ~= hi + lo, residual ~2^-18 rel
__device__ __forceinline__ void split2(float x, ushort& hi, ushort& lo) {
  ushort h = bf16_rtne(x);
  float hf = __uint_as_float(((unsigned)h) << 16);
  hi = h;
  lo = bf16_rtne(x - hf);
}

// ---------------------------------------------------------------------------
// K1: per (b,l): a_words = mean(x); logits = w_route_ws[l] . x; softmax;
//     wls = c_ws * a_words.
// ---------------------------------------------------------------------------
__global__ __launch_bounds__(256) void k1_route_words(
    const float* __restrict__ tf, const float* __restrict__ wr,
    float* __restrict__ wls, float* __restrict__ a_words) {
  int bl = blockIdx.x;
  int l  = bl & (L - 1);
  int t  = threadIdx.x;
  int wave = t >> 6, lane = t & 63;
  __shared__ float sx[D];
  __shared__ float slog[NS];
  __shared__ float s_aw;
  sx[t] = tf[bl * D + t];
  __syncthreads();
  const float* wbase = wr + l * NS * D;
#pragma unroll
  for (int r = 0; r < 8; ++r) {
    int n = wave * 8 + r;
    const float* w = wbase + n * D;
    float p = 0.f;
#pragma unroll
    for (int jj = 0; jj < 4; ++jj) {
      int j = lane + jj * 64;
      p = fmaf(w[j], sx[j], p);
    }
    p = wave_reduce_sum(p);
    if (lane == 0) slog[n] = p;
  }
  if (wave == 0) {
    float p = sx[lane] + sx[lane + 64] + sx[lane + 128] + sx[lane + 192];
    p = wave_reduce_sum(p);
    if (lane == 0) s_aw = p * (1.f / D);
  }
  __syncthreads();
  if (wave == 0) {
    float aw = s_aw;
    float v = (lane < NS) ? slog[lane] : -INFINITY;
    float m = wave_reduce_max(v);
    float e = (lane < NS) ? __expf(v - m) : 0.f;
    float s = wave_reduce_sum(e);
    if (lane < NS) wls[bl * NS + lane] = (e / s) * aw;
    if (lane == 0) a_words[bl] = aw;
  }
}

// ---------------------------------------------------------------------------
// K2: weighted_c[b,s] = sum_l wls; a_slots = weighted_c / sum_l a_words.
// ---------------------------------------------------------------------------
__global__ __launch_bounds__(64) void k2_slots_agg(
    const float* __restrict__ wls, const float* __restrict__ a_words,
    float* __restrict__ weighted_c, float* __restrict__ a_slots) {
  int b = blockIdx.x;
  int lane = threadIdx.x;
  float aw = a_words[b * L + lane];
  float sa = wave_reduce_sum(aw);
  if (lane < NS) {
    float wc = 0.f;
    for (int l = 0; l < L; ++l) wc += wls[(b * L + l) * NS + lane];
    weighted_c[b * NS + lane] = wc;
    a_slots[b * NS + lane] = wc / sa;
  }
}

// ---------------------------------------------------------------------------
// K3: split-bf16 MFMA GEMM. Per (s, i-tile, l-chunk):
//   part[sp,s,b,i] = sum_{l in chunk, j} Wp[l,s,i,j] * (wls[b,l,s]*x[b,l,j])
// BM=128 (all b -> W read exactly once), BN=128, KC=64, 256 thr / 4 waves,
// each wave owns a 64x64 quadrant (4x4 fragments of 16x16x32 MFMA).
// fp32 emulated via hi/lo bf16: Ah*Bh + Ah*Bl + Al*Bh (Al*Bl ~2^-18, dropped).
// ---------------------------------------------------------------------------
#define BM 128
#define BN 128
#define KC 64
#define KP 72  // KC + 8 ushort pad: row stride 144B breaks bank aliasing

__global__ __launch_bounds__(256) void k3_mfma(
    const float* __restrict__ tf, const float* __restrict__ wp,
    const float* __restrict__ wls, float* __restrict__ part, int nsplit) {
  __shared__ ushort Ah[BM][KP], Al[BM][KP], Wh[BN][KP], Wl[BN][KP];
  __shared__ float sw[BM];

  int bx   = blockIdx.x;
  int sp   = bx % nsplit;
  int rest = bx / nsplit;
  int it   = rest & 1;
  int s    = rest >> 1;
  int i0   = it * BN;
  int lchunk = L / nsplit;
  int l0     = sp * lchunk;

  int t    = threadIdx.x;
  int jq   = (t & 15) * 4;  // j quad within KC
  int rb   = t >> 4;        // staging row base
  int lane = t & 63;
  int w    = t >> 6;
  int wm   = w >> 1, wn = w & 1;
  int arow = wm * 64 + (lane & 15);
  int brow = wn * 64 + (lane & 15);
  int ko   = (lane >> 4) * 8;

  f32x4 acc[4][4];
#pragma unroll
  for (int i = 0; i < 4; ++i)
#pragma unroll
    for (int j = 0; j < 4; ++j) acc[i][j] = (f32x4)0.f;

  for (int li = 0; li < lchunk; ++li) {
    int l = l0 + li;
    __syncthreads();  // previous step's MFMA done; sw consumers done
    if (t < BM) sw[t] = wls[((size_t)t * L + l) * NS + s];
    __syncthreads();  // sw visible
    const float* wbase = wp + (size_t)(l * NS + s) * (D * D);
    for (int jc = 0; jc < D; jc += KC) {
      if (jc) __syncthreads();  // previous MFMA done before overwrite
      // stage A (hi/lo): A[b][j] = wls[b,l,s] * x[b,l,jc+j]
#pragma unroll
      for (int p = 0; p < 8; ++p) {
        int bb = p * 16 + rb;
        const float4 v = *(const float4*)(tf + ((size_t)bb * L + l) * D + jc + jq);
        float sc = sw[bb];
        ushort4 h4, l4;
        split2(v.x * sc, h4.x, l4.x);
        split2(v.y * sc, h4.y, l4.y);
        split2(v.z * sc, h4.z, l4.z);
        split2(v.w * sc, h4.w, l4.w);
        *(ushort4*)&Ah[bb][jq] = h4;
        *(ushort4*)&Al[bb][jq] = l4;
      }
      // stage W (hi/lo): W[i][j] = Wp[l,s,i0+i,jc+j]
#pragma unroll
      for (int p = 0; p < 8; ++p) {
        int ii = p * 16 + rb;
        const float4 v = *(const float4*)(wbase + (size_t)(i0 + ii) * D + jc + jq);
        ushort4 h4, l4;
        split2(v.x, h4.x, l4.x);
        split2(v.y, h4.y, l4.y);
        split2(v.z, h4.z, l4.z);
        split2(v.w, h4.w, l4.w);
        *(ushort4*)&Wh[ii][jq] = h4;
        *(ushort4*)&Wl[ii][jq] = l4;
      }
      __syncthreads();
#pragma unroll
      for (int k32 = 0; k32 < 2; ++k32) {
        int kb = k32 * 32 + ko;
        bf16x8 ah[4], av[4], bh[4], bv[4];
#pragma unroll
        for (int mi = 0; mi < 4; ++mi) {
          ah[mi] = *(const bf16x8*)&Ah[arow + mi * 16][kb];
          av[mi] = *(const bf16x8*)&Al[arow + mi * 16][kb];
        }
#pragma unroll
        for (int ni = 0; ni < 4; ++ni) {
          bh[ni] = *(const bf16x8*)&Wh[brow + ni * 16][kb];
          bv[ni] = *(const bf16x8*)&Wl[brow + ni * 16][kb];
        }
#pragma unroll
        for (int mi = 0; mi < 4; ++mi)
#pragma unroll
          for (int ni = 0; ni < 4; ++ni) {
            acc[mi][ni] = __builtin_amdgcn_mfma_f32_16x16x32_bf16(
                ah[mi], bh[ni], acc[mi][ni], 0, 0, 0);
            acc[mi][ni] = __builtin_amdgcn_mfma_f32_16x16x32_bf16(
                ah[mi], bv[ni], acc[mi][ni], 0, 0, 0);
            acc[mi][ni] = __builtin_amdgcn_mfma_f32_16x16x32_bf16(
                av[mi], bh[ni], acc[mi][ni], 0, 0, 0);
          }
      }
    }
  }
  // epilogue: write partials (divide happens in reduce kernel)
  float* pout = part + (((size_t)sp * NS + s) * B) * D + i0;
#pragma unroll
  for (int mi = 0; mi < 4; ++mi)
#pragma unroll
    for (int ni = 0; ni < 4; ++ni) {
      int col = wn * 64 + ni * 16 + (lane & 15);
#pragma unroll
      for (int r = 0; r < 4; ++r) {
        int bb = wm * 64 + mi * 16 + (lane >> 4) * 4 + r;
        pout[(size_t)bb * D + col] = acc[mi][ni][r];
      }
    }
}

// ---------------------------------------------------------------------------
// K3R: u_slots[b,s,i] = (sum_sp part[sp,s,b,i]) / weighted_c[b,s]
// ---------------------------------------------------------------------------
__global__ __launch_bounds__(256) void k3r_reduce(
    const float* __restrict__ part, const float* __restrict__ wc,
    float* __restrict__ u_slots, int nsplit) {
  int idx = blockIdx.x * 256 + threadIdx.x;  // over (s,b,i)
  int i  = idx & (D - 1);
  int sb = idx >> 8;
  int b  = sb & (B - 1);
  int s  = sb >> 7;
  float v = 0.f;
  for (int sp = 0; sp < nsplit; ++sp)
    v += part[(size_t)sp * (NS * B * D) + idx];
  u_slots[((size_t)b * NS + s) * D + i] = v / wc[b * NS + s];
}

// ---------------------------------------------------------------------------
// K4: per (b,s): logits2 = w_route_si[s] . u_slots[b,s]; softmax over NI;
//     w2 = c_si * a_slots.
// ---------------------------------------------------------------------------
__global__ __launch_bounds__(64) void k4_route_si(
    const float* __restrict__ u_slots, const float* __restrict__ wr_si,
    const float* __restrict__ a_slots, float* __restrict__ w2) {
  int bs = blockIdx.x;
  int s  = bs & (NS - 1);
  int lane = threadIdx.x;
  __shared__ float su[D];
  __shared__ float slog[NI];
#pragma unroll
  for (int jj = 0; jj < 4; ++jj) su[lane + jj * 64] = u_slots[bs * D + lane + jj * 64];
  __syncthreads();
  for (int i = 0; i < NI; ++i) {
    const float* w = wr_si + (s * NI + i) * D;
    float p = 0.f;
#pragma unroll
    for (int jj = 0; jj < 4; ++jj) {
      int j = lane + jj * 64;
      p = fmaf(w[j], su[j], p);
    }
    p = wave_reduce_sum(p);
    if (lane == 0) slog[i] = p;
  }
  __syncthreads();
  float v = (lane < NI) ? slog[lane] : -INFINITY;
  float m = wave_reduce_max(v);
  float e = (lane < NI) ? __expf(v - m) : 0.f;
  float ssum = wave_reduce_sum(e);
  if (lane < NI) w2[bs * NI + lane] = (e / ssum) * a_slots[bs];
}

// ---------------------------------------------------------------------------
// K5: wc2[b,i] = sum_s w2; a_intents = wc2 / sum_s a_slots.
// ---------------------------------------------------------------------------
__global__ __launch_bounds__(64) void k5_intents_agg(
    const float* __restrict__ w2, const float* __restrict__ a_slots,
    float* __restrict__ wc2, float* __restrict__ a_intents) {
  int b = blockIdx.x;
  int lane = threadIdx.x;
  float as = (lane < NS) ? a_slots[b * NS + lane] : 0.f;
  float sas = wave_reduce_sum(as);
  if (lane < NI) {
    float wc = 0.f;
    for (int s = 0; s < NS; ++s) wc += w2[(b * NS + s) * NI + lane];
    wc2[b * NI + lane] = wc;
    a_intents[b * NI + lane] = wc / sas;
  }
}

// ---------------------------------------------------------------------------
// K6: Wsum[s,i,k] = sum_j w_pose_si[s,i,j,k] (float4-vectorized over k).
// ---------------------------------------------------------------------------
__global__ __launch_bounds__(256) void k6_wsum(
    const float* __restrict__ wps, float* __restrict__ wsum) {
  __shared__ float red[4][D];
  int si = blockIdx.x;
  int t  = threadIdx.x;
  int k4 = (t & 63) * 4;
  int jg = t >> 6;
  const float* base = wps + (size_t)si * D * D;
  float4 acc = {0.f, 0.f, 0.f, 0.f};
  for (int j = jg; j < D; j += 4) {
    float4 v = *(const float4*)(base + (size_t)j * D + k4);
    acc.x += v.x; acc.y += v.y; acc.z += v.z; acc.w += v.w;
  }
  *(float4*)&red[jg][k4] = acc;
  __syncthreads();
  wsum[si * D + t] = (red[0][t] + red[1][t]) + (red[2][t] + red[3][t]);
}

// ---------------------------------------------------------------------------
// K7: u_intents[b,i,k] = sum_s w2[b,s,i]*u_slots[b,s,k]*Wsum[s,i,k] / wc2[b,i]
// ---------------------------------------------------------------------------
__global__ __launch_bounds__(256) void k7_uintents(
    const float* __restrict__ u_slots, const float* __restrict__ w2,
    const float* __restrict__ wsum, const float* __restrict__ wc2,
    float* __restrict__ u_intents) {
  int bi = blockIdx.x;
  int b = bi >> 4, i = bi & (NI - 1);
  int k = threadIdx.x;
  float acc = 0.f;
  for (int s = 0; s < NS; ++s) {
    float w = w2[(b * NS + s) * NI + i];
    acc = fmaf(w * u_slots[(b * NS + s) * D + k], wsum[(s * NI + i) * D + k], acc);
  }
  u_intents[bi * D + k] = acc / wc2[bi];
}

// ---------------------------------------------------------------------------
extern "C" void kernel_launch(void* const* d_in, const int* in_sizes, int n_in,
                              void* d_out, int out_size, void* d_ws, size_t ws_size,
                              hipStream_t stream) {
  const float* tf    = (const float*)d_in[0];  // (B,L,D)
  const float* wr_ws = (const float*)d_in[1];  // (L,NS,D)
  const float* wp_ws = (const float*)d_in[2];  // (L,NS,D,D)
  const float* wr_si = (const float*)d_in[3];  // (NS,NI,D)
  const float* wp_si = (const float*)d_in[4];  // (NS,NI,D,D)

  float* out       = (float*)d_out;
  float* a_slots   = out;                      // B*NS
  float* u_slots   = a_slots + B * NS;         // B*NS*D
  float* a_intents = u_slots + B * NS * D;     // B*NI
  float* u_intents = a_intents + B * NI;       // B*NI*D

  float* ws         = (float*)d_ws;
  float* wls        = ws;                      // B*L*NS  = 262144
  float* a_words    = wls + B * L * NS;        // B*L     = 8192
  float* weighted_c = a_words + B * L;         // B*NS    = 4096
  float* w2         = weighted_c + B * NS;     // B*NS*NI = 65536
  float* wc2        = w2 + B * NS * NI;        // B*NI    = 2048
  float* wsum       = wc2 + B * NI;            // NS*NI*D = 131072
  float* part       = wsum + NS * NI * D;      // nsplit * NS*B*D

  const size_t base_f  = 473088;               // floats before `part`
  const size_t chunk_f = (size_t)NS * B * D;   // 1,048,576 floats per split
  size_t avail_f = ws_size / sizeof(float);
  int nsplit = 1;
  if (avail_f >= base_f + 8 * chunk_f)      nsplit = 8;
  else if (avail_f >= base_f + 4 * chunk_f) nsplit = 4;
  else if (avail_f >= base_f + 2 * chunk_f) nsplit = 2;

  k1_route_words<<<B * L, 256, 0, stream>>>(tf, wr_ws, wls, a_words);
  k2_slots_agg<<<B, 64, 0, stream>>>(wls, a_words, weighted_c, a_slots);
  k3_mfma<<<64 * nsplit, 256, 0, stream>>>(tf, wp_ws, wls, part, nsplit);
  k3r_reduce<<<(NS * B * D) / 256, 256, 0, stream>>>(part, weighted_c, u_slots, nsplit);
  k6_wsum<<<NS * NI, 256, 0, stream>>>(wp_si, wsum);
  k4_route_si<<<B * NS, 64, 0, stream>>>(u_slots, wr_si, a_slots, w2);
  k5_intents_agg<<<B, 64, 0, stream>>>(w2, a_slots, wc2, a_intents);
  k7_uintents<<<B * NI, 256, 0, stream>>>(u_slots, w2, wsum, wc2, u_intents);
}